// Round 2
// 493.043 us; speedup vs baseline: 1.0675x; 1.0675x over previous
//
#include <hip/hip_runtime.h>

// Izhikevich scan: 16384 chains x 2000 steps. Structurally 1 wave/CU of real
// work (256 waves), so R1/R2 were latency-bound at ~300 cyc/step: the single
// compute wave's in-order vmcnt queue (3 stores/step + staging) serialized
// memory latency into the dependency chain.
//
// R3 (resubmit; R3a bench was an infra failure, no data): 4 waves/block.
//   w0,w1,w2: REDUNDANTLY compute the identical chain (idle SIMDs => free),
//             each stores exactly ONE plane (s/v/u). Store-only vmcnt queue,
//             never waited on, never full. Step = ds_read + ~17 VALU + 1 store.
//   w3:       input stager only: double-buffered global_load_lds(16B) chunks,
//             private vmcnt(0) before each barrier.
// Raw s_barrier (asm + "memory" clobber) instead of __syncthreads so compute
// waves do NOT drain their stores at chunk boundaries (no implicit vmcnt(0)).
// Barrier counts match across branches: 1 prologue + NCHUNK per wave.
// Race audit: compute's chunk-c ds_reads are all consumed (lgkmcnt(0)) before
// its barrier; stager overwrites buffer (c+2)&1 only after that barrier.
//
// NUMERICS: exact numpy op order, fp contract off (spike flips cost O(100)).

#define NSTEPS 2000
#define NNEUR  512
#define BATCH  32
#define INPLANE 1024000u                       // NSTEPS*NNEUR per batch
#define PLANE  32768000u                       // BATCH*NSTEPS*NNEUR per out plane
#define CHUNK  100
#define NCHUNK (NSTEPS / CHUNK)                // 20
#define NG     (CHUNK / 4)                     // 25 groups of 4 steps

typedef const __attribute__((address_space(1))) unsigned GPtr;
typedef __attribute__((address_space(3))) unsigned LPtr;

__device__ __forceinline__ void izh_step(float i_t, float& v, float& u, float& s) {
#pragma clang fp contract(off)
    float t1 = 0.04f * v;
    t1 = t1 * v;
    float t2 = 5.0f * v;
    float acc = t1 + t2;
    acc = acc + 140.0f;
    acc = acc - u;
    acc = acc + i_t;
    float dv = acc * 0.5f;
    float t4 = 0.2f * v;
    t4 = t4 - u;
    t4 = 0.02f * t4;
    float du = t4 * 0.5f;
    v = v + dv;
    u = u + du;
    bool sp = (v >= 30.0f);
    s = sp ? 1.0f : 0.0f;
    v = sp ? -65.0f : v;
    u = sp ? (u + 8.0f) : u;
}

// One compute wave: full recurrence, stores only plane W (0=s, 1=v, 2=u).
template <int W>
__device__ __forceinline__ void run_compute(const float (*lin)[CHUNK * 64], int lane,
                                            unsigned voff, float* __restrict__ out) {
    float* oplane = out + (size_t)W * PLANE;
    float v = -65.0f;
    float u = -13.0f;                          // B*C exactly

    asm volatile("s_barrier" ::: "memory");    // matches stager's prologue barrier
    for (int c = 0; c < NCHUNK; ++c) {
        const float* lbuf = &lin[c & 1][0];
        float ra[4], rb[4];
#pragma unroll
        for (int j = 0; j < 4; ++j) ra[j] = lbuf[j * 64 + lane];

        for (int g = 0; g < NG - 1; g += 2) {
            // prefetch group g+1 while computing group g
#pragma unroll
            for (int j = 0; j < 4; ++j) rb[j] = lbuf[(4 * (g + 1) + j) * 64 + lane];
#pragma unroll
            for (int j = 0; j < 4; ++j) {
                float s;
                izh_step(ra[j], v, u, s);
                oplane[voff] = (W == 0) ? s : (W == 1) ? v : u;
                voff += NNEUR;
            }
            if (g + 2 < NG) {
#pragma unroll
                for (int j = 0; j < 4; ++j) ra[j] = lbuf[(4 * (g + 2) + j) * 64 + lane];
            }
#pragma unroll
            for (int j = 0; j < 4; ++j) {
                float s;
                izh_step(rb[j], v, u, s);
                oplane[voff] = (W == 0) ? s : (W == 1) ? v : u;
                voff += NNEUR;
            }
        }
        // tail group NG-1 (NG odd), already in ra
#pragma unroll
        for (int j = 0; j < 4; ++j) {
            float s;
            izh_step(ra[j], v, u, s);
            oplane[voff] = (W == 0) ? s : (W == 1) ? v : u;
            voff += NNEUR;
        }
        asm volatile("s_barrier" ::: "memory");
    }
}

__global__ __launch_bounds__(256, 1) void izh_kernel(const float* __restrict__ in,
                                                     float* __restrict__ out) {
    __shared__ float lin[2][CHUNK * 64];       // 2 x 25.6 KB input staging

    const int tid  = threadIdx.x;
    const int w    = tid >> 6;                 // wave id 0..3
    const int lane = tid & 63;
    const unsigned n0 = (unsigned)((blockIdx.x * 64) & (NNEUR - 1)); // neuron base
    const unsigned b  = (unsigned)((unsigned)(blockIdx.x * 64) >> 9); // batch (uniform)

    if (w == 3) {
        // ---- stager wave: double-buffered global_load_lds, own vmcnt only ----
        // lane L covers step (L>>4), 16B at neurons n0 + (L&15)*4; one
        // global_load_lds(16) stages 4 steps x 64 neurons, LDS step-major.
        const float* gsrc = in + (size_t)b * INPLANE
                               + (size_t)(lane >> 4) * NNEUR
                               + n0 + (size_t)(lane & 15) * 4;
#pragma unroll
        for (int g = 0; g < NG; ++g) {
            __builtin_amdgcn_global_load_lds((GPtr*)(gsrc + (size_t)(4 * g) * NNEUR),
                                             (LPtr*)&lin[0][g * 256], 16, 0, 0);
        }
        asm volatile("s_waitcnt vmcnt(0)" ::: "memory");
        asm volatile("s_barrier" ::: "memory");          // chunk 0 ready

        for (int c = 0; c < NCHUNK; ++c) {
            if (c + 1 < NCHUNK) {
                const float* gs = gsrc + (size_t)(c + 1) * CHUNK * NNEUR;
                float* lb = &lin[(c + 1) & 1][0];
#pragma unroll
                for (int g = 0; g < NG; ++g) {
                    __builtin_amdgcn_global_load_lds((GPtr*)(gs + (size_t)(4 * g) * NNEUR),
                                                     (LPtr*)(lb + g * 256), 16, 0, 0);
                }
                asm volatile("s_waitcnt vmcnt(0)" ::: "memory");
            }
            asm volatile("s_barrier" ::: "memory");      // chunk c+1 ready / c consumed
        }
    } else {
        // ---- compute waves: identical redundant chain, one plane each ----
        const unsigned voff0 = b * INPLANE + n0 + (unsigned)lane;
        if (w == 0)      run_compute<0>(lin, lane, voff0, out);
        else if (w == 1) run_compute<1>(lin, lane, voff0, out);
        else             run_compute<2>(lin, lane, voff0, out);
    }
}

extern "C" void kernel_launch(void* const* d_in, const int* in_sizes, int n_in,
                              void* d_out, int out_size, void* d_ws, size_t ws_size,
                              hipStream_t stream) {
    const float* in = (const float*)d_in[0];
    float* out = (float*)d_out;
    izh_kernel<<<(BATCH * NNEUR) / 64, 256, 0, stream>>>(in, out);
}

// Round 3
// 491.164 us; speedup vs baseline: 1.0716x; 1.0038x over previous
//
#include <hip/hip_runtime.h>

// Izhikevich scan: 16384 chains x 2000 steps, 256 waves of real work.
// R3 post-mortem (243us izh, ~292 cyc/step): per-step global stores serialize
// via the store-data VGPR reuse rule -- HW requires store source regs intact
// until vmcnt retire; regalloc reuses the same reg next step, so the waitcnt
// pass emits ~vmcnt(0) per step => every step eats ~300cyc store latency.
//
// R4: decouple stores from the recurrence. Compute waves write each step's
// value to a WAVE-PRIVATE LDS out-buffer (ds_write_b32, short lgkm latency),
// and every WIN=20 steps do a transpose readback (5x ds_read_b128) + 5x
// global_store_dwordx4. Store data regs are reused one window (~20 steps)
// later => vmcnt waits pre-satisfied; stores pace at write BW, not latency.
//   w0,w1,w2: redundant compute (idle SIMDs), one output plane each (s/v/u).
//   w3:       input stager (double-buffered global_load_lds, own vmcnt(0)).
// Raw s_barrier protocol unchanged from R3 (1 prologue + NCHUNK per wave).
//
// NUMERICS: exact numpy op order, fp contract off; values round-trip LDS
// bit-exactly.

#define NSTEPS 2000
#define NNEUR  512
#define BATCH  32
#define INPLANE 1024000u                       // NSTEPS*NNEUR per batch
#define PLANE  32768000u                       // BATCH*NSTEPS*NNEUR per out plane
#define CHUNK  100
#define NCHUNK (NSTEPS / CHUNK)                // 20
#define NG     (CHUNK / 4)                     // 25 staging groups of 4 steps
#define WIN    20                              // out-staging window (steps)
#define NWIN   (CHUNK / WIN)                   // 5

typedef const __attribute__((address_space(1))) unsigned GPtr;
typedef __attribute__((address_space(3))) unsigned LPtr;

__device__ __forceinline__ void izh_step(float i_t, float& v, float& u, float& s) {
#pragma clang fp contract(off)
    float t1 = 0.04f * v;
    t1 = t1 * v;
    float t2 = 5.0f * v;
    float acc = t1 + t2;
    acc = acc + 140.0f;
    acc = acc - u;
    acc = acc + i_t;
    float dv = acc * 0.5f;
    float t4 = 0.2f * v;
    t4 = t4 - u;
    t4 = 0.02f * t4;
    float du = t4 * 0.5f;
    v = v + dv;
    u = u + du;
    bool sp = (v >= 30.0f);
    s = sp ? 1.0f : 0.0f;
    v = sp ? -65.0f : v;
    u = sp ? (u + 8.0f) : u;
}

// One compute wave: full recurrence, stores only plane W (0=s, 1=v, 2=u).
// ob: this wave's private LDS staging [2 bufs][WIN steps][64 neurons].
template <int W>
__device__ __forceinline__ void run_compute(const float (*lin)[CHUNK * 64],
                                            float (*ob)[WIN][64],
                                            int lane, unsigned obase,
                                            float* __restrict__ out) {
    float* oplane = out + (size_t)W * PLANE;
    float v = -65.0f;
    float u = -13.0f;                          // B*C exactly
    const int r0 = lane >> 4;                  // flush: step-in-quad
    const int c4 = (lane & 15) * 4;            // flush: neuron quad base
    int buf = 0;

    asm volatile("s_barrier" ::: "memory");    // matches stager's prologue barrier
    for (int c = 0; c < NCHUNK; ++c) {
        const float* lbuf = &lin[c & 1][0];
        for (int w = 0; w < NWIN; ++w) {
            // bulk-load this window's inputs (20 ds_read_b32, overlap w/ chain)
            float ri[WIN];
#pragma unroll
            for (int j = 0; j < WIN; ++j) ri[j] = lbuf[(w * WIN + j) * 64 + lane];
            // recurrence; per-step value goes to LDS (fire-and-forget lgkm)
#pragma unroll
            for (int j = 0; j < WIN; ++j) {
                float s;
                izh_step(ri[j], v, u, s);
                ob[buf][j][lane] = (W == 0) ? s : (W == 1) ? v : u;
            }
            // flush window: transpose read + batched 16B stores.
            // lane L -> steps r0+4i, neurons c4..c4+3; data regs reused only
            // next window => vmcnt waits land pre-satisfied.
            const unsigned step0 = (unsigned)(c * CHUNK + w * WIN);
#pragma unroll
            for (int i = 0; i < WIN / 4; ++i) {
                float4 d = *(const float4*)&ob[buf][r0 + 4 * i][c4];
                size_t goff = (size_t)obase
                            + (size_t)(step0 + (unsigned)(r0 + 4 * i)) * NNEUR
                            + (size_t)(unsigned)c4;
                *(float4*)(oplane + goff) = d;
            }
            buf ^= 1;
        }
        asm volatile("s_barrier" ::: "memory");
    }
}

__global__ __launch_bounds__(256, 1) void izh_kernel(const float* __restrict__ in,
                                                     float* __restrict__ out) {
    __shared__ float lin[2][CHUNK * 64];       // 51.2 KB input staging
    __shared__ float ob[3][2][WIN][64];        // 30.7 KB output staging (per-wave)

    const int tid  = threadIdx.x;
    const int w    = tid >> 6;                 // wave id 0..3
    const int lane = tid & 63;
    const unsigned n0 = (unsigned)((blockIdx.x * 64) & (NNEUR - 1)); // neuron base
    const unsigned b  = (unsigned)((unsigned)(blockIdx.x * 64) >> 9); // batch (uniform)

    if (w == 3) {
        // ---- stager wave: double-buffered global_load_lds, own vmcnt only ----
        // lane L covers step (L>>4), 16B at neurons n0 + (L&15)*4; one
        // global_load_lds(16) stages 4 steps x 64 neurons, LDS step-major.
        const float* gsrc = in + (size_t)b * INPLANE
                               + (size_t)(lane >> 4) * NNEUR
                               + n0 + (size_t)(lane & 15) * 4;
#pragma unroll
        for (int g = 0; g < NG; ++g) {
            __builtin_amdgcn_global_load_lds((GPtr*)(gsrc + (size_t)(4 * g) * NNEUR),
                                             (LPtr*)&lin[0][g * 256], 16, 0, 0);
        }
        asm volatile("s_waitcnt vmcnt(0)" ::: "memory");
        asm volatile("s_barrier" ::: "memory");          // chunk 0 ready

        for (int c = 0; c < NCHUNK; ++c) {
            if (c + 1 < NCHUNK) {
                const float* gs = gsrc + (size_t)(c + 1) * CHUNK * NNEUR;
                float* lb = &lin[(c + 1) & 1][0];
#pragma unroll
                for (int g = 0; g < NG; ++g) {
                    __builtin_amdgcn_global_load_lds((GPtr*)(gs + (size_t)(4 * g) * NNEUR),
                                                     (LPtr*)(lb + g * 256), 16, 0, 0);
                }
                asm volatile("s_waitcnt vmcnt(0)" ::: "memory");
            }
            asm volatile("s_barrier" ::: "memory");      // chunk c+1 ready / c consumed
        }
    } else {
        // ---- compute waves: identical redundant chain, one plane each ----
        const unsigned obase = b * INPLANE + n0;
        if (w == 0)      run_compute<0>(lin, ob[0], lane, obase, out);
        else if (w == 1) run_compute<1>(lin, ob[1], lane, obase, out);
        else             run_compute<2>(lin, ob[2], lane, obase, out);
    }
}

extern "C" void kernel_launch(void* const* d_in, const int* in_sizes, int n_in,
                              void* d_out, int out_size, void* d_ws, size_t ws_size,
                              hipStream_t stream) {
    const float* in = (const float*)d_in[0];
    float* out = (float*)d_out;
    izh_kernel<<<(BATCH * NNEUR) / 64, 256, 0, stream>>>(in, out);
}